// Round 2
// baseline (222.427 us; speedup 1.0000x reference)
//
#include <hip/hip_runtime.h>

typedef const float* fcp;

#define C_    256
#define NH_   8
#define DH_   32
#define VV_   6
#define TT_   3
#define VT_   18
#define HWK   1024            // Hin*Win
#define L_    (VT_*HWK)       // 18432 kv tokens
#define SCALE_ 0.17677669529663687f   // 32^-0.5

// ---- workspace layout (float offsets) ----
#define QV_OFF   0        // 256   query vector
#define QP_OFF   256      // 256   projected query
#define EMB_OFF  512      // 18*256 per-(v,t) channel embeds
#define WF_OFF   5120     // 8*256 folded+scaled key weights [h][c]
#define BB_OFF   7168     // 8     folded key-bias terms (scaled)
#define PM_OFF   7200     // 144*8 per-block score maxima
#define PS_OFF   8448     // 72*8  per-block exp partial sums
#define CTX_OFF  9216     // 8*256 unnormalized context [h][c]
#define Y_OFF    11264    // 256   v-projected vector
#define Z_OFF    11520    // 256   o-projected vector
#define SC_OFF   12288    // 8*18432 scores [h][token]
#define PEX_OFF  159744   // 18432*8 exp'd probs [token][h]  (16B aligned)

__device__ __forceinline__ float blockReduceSum256(float v){
  __shared__ float red[4];
  #pragma unroll
  for (int off = 32; off; off >>= 1) v += __shfl_xor(v, off, 64);
  const int lane = threadIdx.x & 63, w = threadIdx.x >> 6;
  __syncthreads();
  if (lane == 0) red[w] = v;
  __syncthreads();
  return red[0] + red[1] + red[2] + red[3];
}

// K0: query vector, per-(v,t) embeds, zero ctx accumulator. 1 block x 256.
__global__ void k_prep0(fcp qe, fcp cam, fcp tpe, fcp spe,
                        const int* __restrict__ cidx, float* __restrict__ ws){
  const int t = threadIdx.x;
  const int ci = cidx[0];
  ws[QV_OFF + t] = qe[t] + cam[ci*C_ + t] + spe[t];
  for (int vt = 0; vt < VT_; vt++){
    const int v = vt / TT_, tt = vt - v*TT_;
    ws[EMB_OFF + vt*C_ + t] = tpe[tt*C_ + t] + cam[v*C_ + t];
  }
  for (int i = 0; i < 8; i++) ws[CTX_OFF + i*C_ + t] = 0.f;
}

// K1: qp = q_w @ qv + q_b. 256 blocks (one row each) x 256.
__global__ void k_qp(fcp qw, fcp qb, float* __restrict__ ws){
  const int r = blockIdx.x, t = threadIdx.x;
  float v = qw[r*C_ + t] * ws[QV_OFF + t];
  v = blockReduceSum256(v);
  if (t == 0) ws[QP_OFF + r] = v + qb[r];
}

// K2: fold qp into k_w per head: w_h[c] = scale * sum_d qp[h,d]*k_w[h*32+d][c].
// 8 blocks (one head) x 256 (c).
__global__ void k_fold(fcp kw, fcp kb, float* __restrict__ ws){
  const int h = blockIdx.x, c = threadIdx.x;
  float acc = 0.f;
  for (int d = 0; d < DH_; d++)
    acc += ws[QP_OFF + h*DH_ + d] * kw[(size_t)(h*DH_ + d)*C_ + c];
  ws[WF_OFF + h*C_ + c] = SCALE_ * acc;
  if (c == 0){
    float bb = 0.f;
    for (int d = 0; d < DH_; d++) bb += ws[QP_OFF + h*DH_ + d] * kb[h*DH_ + d];
    ws[BB_OFF + h] = SCALE_ * bb;
  }
}

// K3: scores[h][token] = sum_c feats[c,token]*w_h[c] + base[vt][h]; per-block max.
// 144 blocks = 18 (v,t) x 8 s-chunks of 128; 128 threads (2 waves).
__global__ void k_scores(fcp feats, float* __restrict__ ws){
  __shared__ __align__(16) float wf[C_*8];   // [c][h]
  __shared__ float basef[8];
  __shared__ float red[16];
  const int bid = blockIdx.x, vt = bid >> 3, sc = bid & 7, t = threadIdx.x;

  for (int i = t; i < C_*8; i += 128) wf[i] = ws[WF_OFF + (i & 7)*C_ + (i >> 3)];
  __syncthreads();

  // base[h] = sum_c emb[vt][c]*w_h[c] (+ folded key-bias)
  float pb[8] = {0,0,0,0,0,0,0,0};
  for (int c = t; c < C_; c += 128){
    const float e = ws[EMB_OFF + vt*C_ + c];
    #pragma unroll
    for (int h = 0; h < 8; h++) pb[h] += e * wf[c*8 + h];
  }
  #pragma unroll
  for (int h = 0; h < 8; h++){
    float v = pb[h];
    #pragma unroll
    for (int off = 32; off; off >>= 1) v += __shfl_xor(v, off, 64);
    if ((t & 63) == 0) red[(t >> 6)*8 + h] = v;
  }
  __syncthreads();
  if (t < 8) basef[t] = red[t] + red[8 + t] + ws[BB_OFF + t];
  __syncthreads();

  const int g = vt*HWK + sc*128 + t;
  fcp fp = feats + (size_t)vt*C_*HWK + sc*128 + t;
  float acc[8] = {0,0,0,0,0,0,0,0};
  for (int c = 0; c < C_; c++){
    const float fv = fp[(size_t)c*HWK];               // coalesced over s
    const float4 wa = *(const float4*)&wf[c*8];       // uniform LDS broadcast
    const float4 wb = *(const float4*)&wf[c*8 + 4];
    acc[0] += fv*wa.x; acc[1] += fv*wa.y; acc[2] += fv*wa.z; acc[3] += fv*wa.w;
    acc[4] += fv*wb.x; acc[5] += fv*wb.y; acc[6] += fv*wb.z; acc[7] += fv*wb.w;
  }
  #pragma unroll
  for (int h = 0; h < 8; h++){
    const float s = acc[h] + basef[h];
    ws[SC_OFF + h*L_ + g] = s;
    float v = s;
    #pragma unroll
    for (int off = 32; off; off >>= 1) v = fmaxf(v, __shfl_xor(v, off, 64));
    if ((t & 63) == 0) red[(t >> 6)*8 + h] = v;
  }
  __syncthreads();
  if (t < 8) ws[PM_OFF + bid*8 + t] = fmaxf(red[t], red[8 + t]);
}

// K4: global max per head, pex[token][h] = exp(score-m), per-block partial sums.
// 72 blocks = 18 (v,t) x 4 s-chunks of 256; 256 threads.
__global__ void k_pexp(float* __restrict__ ws){
  __shared__ float m[8];
  __shared__ float red[32];
  const int bid = blockIdx.x, vt = bid >> 2, sc = bid & 3, t = threadIdx.x;
  if (t < 8){
    float mm = -1e30f;
    for (int i = 0; i < 144; i++) mm = fmaxf(mm, ws[PM_OFF + i*8 + t]);
    m[t] = mm;
  }
  __syncthreads();
  const int g = vt*HWK + sc*256 + t;
  float e[8];
  #pragma unroll
  for (int h = 0; h < 8; h++) e[h] = __expf(ws[SC_OFF + h*L_ + g] - m[h]);
  float4* p4 = (float4*)(ws + PEX_OFF) + (size_t)g*2;
  p4[0] = make_float4(e[0], e[1], e[2], e[3]);
  p4[1] = make_float4(e[4], e[5], e[6], e[7]);
  #pragma unroll
  for (int h = 0; h < 8; h++){
    float v = e[h];
    #pragma unroll
    for (int off = 32; off; off >>= 1) v += __shfl_xor(v, off, 64);
    if ((t & 63) == 0) red[(t >> 6)*8 + h] = v;
  }
  __syncthreads();
  if (t < 8) ws[PS_OFF + bid*8 + t] = red[t] + red[8+t] + red[16+t] + red[24+t];
}

// K5: ctx[h][c] += sum_s pex[s][h]*feats[c][s]. 288 blocks = 18 (v,t) x 16 c-chunks;
// 256 threads = 4 waves, each wave owns 4 channels, lanes run over s.
__global__ void k_ctx(fcp feats, float* __restrict__ ws){
  const int bid = blockIdx.x, vt = bid / 16, cc = bid % 16;
  const int t = threadIdx.x, wv = t >> 6, lane = t & 63;
  const int c0 = cc*16 + wv*4;
  fcp fb = feats + (size_t)vt*C_*HWK;
  const float4* p4 = (const float4*)(ws + PEX_OFF) + (size_t)vt*HWK*2;
  float acc[4][8];
  #pragma unroll
  for (int j = 0; j < 4; j++)
    #pragma unroll
    for (int h = 0; h < 8; h++) acc[j][h] = 0.f;

  for (int step = 0; step < 16; step++){
    const int s = step*64 + lane;
    const float4 pa = p4[s*2], pb = p4[s*2 + 1];   // coalesced 32B/lane
    #pragma unroll
    for (int j = 0; j < 4; j++){
      const float fv = fb[(size_t)(c0 + j)*HWK + s];        // coalesced
      acc[j][0] += fv*pa.x; acc[j][1] += fv*pa.y; acc[j][2] += fv*pa.z; acc[j][3] += fv*pa.w;
      acc[j][4] += fv*pb.x; acc[j][5] += fv*pb.y; acc[j][6] += fv*pb.z; acc[j][7] += fv*pb.w;
    }
  }
  #pragma unroll
  for (int j = 0; j < 4; j++)
    #pragma unroll
    for (int h = 0; h < 8; h++){
      float v = acc[j][h];
      #pragma unroll
      for (int off = 32; off; off >>= 1) v += __shfl_xor(v, off, 64);
      if (lane == j*8 + h) atomicAdd(ws + CTX_OFF + h*C_ + c0 + j, v);
    }
}

// K6: y[r] = v_w[r] . ctx_norm[head(r)] + v_b[r], with embed/denominator correction.
__global__ void k_vproj(fcp vw, fcp vb, float* __restrict__ ws){
  const int r = blockIdx.x, t = threadIdx.x, h = r >> 5;
  float denom = 0.f, embP = 0.f;
  for (int vt = 0; vt < VT_; vt++){
    const float P = ws[PS_OFF + (vt*4+0)*8 + h] + ws[PS_OFF + (vt*4+1)*8 + h]
                  + ws[PS_OFF + (vt*4+2)*8 + h] + ws[PS_OFF + (vt*4+3)*8 + h];
    denom += P;
    embP  += ws[EMB_OFF + vt*C_ + t] * P;
  }
  const float ctxn = (ws[CTX_OFF + h*C_ + t] + embP) / denom;
  float v = vw[(size_t)r*C_ + t] * ctxn;
  v = blockReduceSum256(v);
  if (t == 0) ws[Y_OFF + r] = v + vb[r];
}

// K7: z = o_w @ y + o_b.
__global__ void k_oproj(fcp ow, fcp ob, float* __restrict__ ws){
  const int r = blockIdx.x, t = threadIdx.x;
  float v = ow[(size_t)r*C_ + t] * ws[Y_OFF + t];
  v = blockReduceSum256(v);
  if (t == 0) ws[Z_OFF + r] = v + ob[r];
}

// K8: LayerNorm over channels + broadcast store. 256 blocks (one channel) x 256.
__global__ void k_out(fcp lng, fcp lnb, const float* __restrict__ ws,
                      float* __restrict__ out, int hw){
  const int c = blockIdx.x, t = threadIdx.x;
  const float z = ws[Z_OFF + t];
  const float s  = blockReduceSum256(z);
  const float s2 = blockReduceSum256(z*z);
  const float mu = s * (1.f/C_);
  const float var = s2 * (1.f/C_) - mu*mu;
  const float rs = rsqrtf(var + 1e-5f);
  const float fin = (ws[Z_OFF + c] - mu) * rs * lng[c] + lnb[c];
  float4 pk = make_float4(fin, fin, fin, fin);
  ((float4*)(out + (size_t)c*hw))[t] = pk;   // 4 pixels per thread
}

extern "C" void kernel_launch(void* const* d_in, const int* in_sizes, int n_in,
                              void* d_out, int out_size, void* d_ws, size_t ws_size,
                              hipStream_t stream) {
  fcp feats = (fcp)d_in[0];
  fcp qe    = (fcp)d_in[1];
  fcp cam   = (fcp)d_in[2];
  fcp tpe   = (fcp)d_in[3];
  fcp spe   = (fcp)d_in[4];
  fcp qw    = (fcp)d_in[5];
  fcp qb    = (fcp)d_in[6];
  fcp kw    = (fcp)d_in[7];
  fcp kb    = (fcp)d_in[8];
  fcp vw    = (fcp)d_in[9];
  fcp vb    = (fcp)d_in[10];
  fcp ow    = (fcp)d_in[11];
  fcp ob    = (fcp)d_in[12];
  fcp lng   = (fcp)d_in[13];
  fcp lnb   = (fcp)d_in[14];
  const int* cidx = (const int*)d_in[15];
  float* ws = (float*)d_ws;
  float* out = (float*)d_out;
  const int hw = out_size / C_;   // 1024

  k_prep0 <<<1,   256, 0, stream>>>(qe, cam, tpe, spe, cidx, ws);
  k_qp    <<<256, 256, 0, stream>>>(qw, qb, ws);
  k_fold  <<<8,   256, 0, stream>>>(kw, kb, ws);
  k_scores<<<144, 128, 0, stream>>>(feats, ws);
  k_pexp  <<<72,  256, 0, stream>>>(ws);
  k_ctx   <<<288, 256, 0, stream>>>(feats, ws);
  k_vproj <<<256, 256, 0, stream>>>(vw, vb, ws);
  k_oproj <<<256, 256, 0, stream>>>(ow, ob, ws);
  k_out   <<<256, 256, 0, stream>>>(lng, lnb, ws, out, hw);
}

// Round 3
// 167.264 us; speedup vs baseline: 1.3298x; 1.3298x over previous
//
#include <hip/hip_runtime.h>

typedef const float* fcp;

#define C_    256
#define NH_   8
#define DH_   32
#define VT_   18
#define HWK   1024            // Hin*Win
#define L_    (VT_*HWK)       // 18432 kv tokens
#define SCALE_ 0.17677669529663687f   // 32^-0.5

// ---- workspace layout (float offsets) ----
#define QP_OFF   256      // 256    projected query
#define EMB_OFF  512      // 18*256 per-(v,t) channel embeds
#define PM_OFF   5120     // 288*8  per-block score maxima
#define PS_OFF   7424     // 288*8  per-block exp partial sums
#define CTX_OFF  9728     // 8*256  unnormalized context [h][c]
#define Y_OFF    11776    // 256    v-projected vector
#define Z_OFF    12032    // 256    o-projected vector
#define SC_OFF   12288    // 8*18432 scores [h][token]
#define PEX_OFF  159744   // 18432*8 exp'd probs [token][h] (16B aligned)

__device__ __forceinline__ float blockReduceSum256(float v){
  __shared__ float red[4];
  #pragma unroll
  for (int off = 32; off; off >>= 1) v += __shfl_xor(v, off, 64);
  const int lane = threadIdx.x & 63, w = threadIdx.x >> 6;
  __syncthreads();
  if (lane == 0) red[w] = v;
  __syncthreads();
  return red[0] + red[1] + red[2] + red[3];
}

// K1: qp = q_w @ qv + q_b (qv built redundantly per block in LDS).
// blocks r<18 also write per-(v,t) embeds; block 255 zeros ctx. 256 blocks x 256.
__global__ void k_qp(fcp qe, fcp cam, fcp tpe, fcp spe, const int* __restrict__ cidx,
                     fcp qw, fcp qb, float* __restrict__ ws){
  __shared__ float qvS[C_];
  const int r = blockIdx.x, t = threadIdx.x;
  const int ci = cidx[0];
  qvS[t] = qe[t] + cam[ci*C_ + t] + spe[t];
  __syncthreads();
  if (r < VT_){
    const int v = r/3, tt = r - v*3;
    ws[EMB_OFF + r*C_ + t] = tpe[tt*C_ + t] + cam[v*C_ + t];
  }
  if (r == 255){
    #pragma unroll
    for (int i = 0; i < 8; i++) ws[CTX_OFF + i*C_ + t] = 0.f;
  }
  float v = qw[r*C_ + t] * qvS[t];
  v = blockReduceSum256(v);
  if (t == 0) ws[QP_OFF + r] = v + qb[r];
}

// K2: fused fold + scores. 288 blocks = 18 vt x 16 s-chunks of 64; 256 threads.
// Phase 1: fold qp into k_w (redundant per block, L2-resident k_w).
// Phase 2: 4-way channel-split dot, LDS combine; per-block max per head.
__global__ void k_scores(fcp feats, fcp kw, fcp kb, float* __restrict__ ws){
  __shared__ __align__(16) float wf[C_*8];   // [c][h]
  __shared__ float qpS[C_];
  __shared__ float bbS[8];
  __shared__ float redS[32];
  __shared__ float basef[8];
  __shared__ float pred[4*512];              // [cg][h*64+s]
  const int bid = blockIdx.x, vt = bid >> 4, sc = bid & 15, t = threadIdx.x;

  qpS[t] = ws[QP_OFF + t];
  __syncthreads();
  { // fold: wf[c][h] = scale * sum_d qp[h*32+d]*k_w[h*32+d][c]
    const int c = t;
    float facc[8] = {0,0,0,0,0,0,0,0};
    #pragma unroll
    for (int h = 0; h < 8; h++){
      #pragma unroll 8
      for (int d = 0; d < DH_; d++)
        facc[h] += qpS[h*DH_ + d] * kw[(size_t)(h*DH_ + d)*C_ + c];
    }
    #pragma unroll
    for (int h = 0; h < 8; h++) wf[c*8 + h] = SCALE_ * facc[h];
    if (t < 8){
      float bb = 0.f;
      for (int d = 0; d < DH_; d++) bb += qpS[t*DH_ + d] * kb[t*DH_ + d];
      bbS[t] = SCALE_ * bb;
    }
  }
  __syncthreads();
  { // base[h] = sum_c emb[vt][c]*wf[c][h] + bb[h]
    const float e = ws[EMB_OFF + vt*C_ + t];
    const float4 wa = *(const float4*)&wf[t*8];
    const float4 wb = *(const float4*)&wf[t*8 + 4];
    float pb[8] = {e*wa.x, e*wa.y, e*wa.z, e*wa.w, e*wb.x, e*wb.y, e*wb.z, e*wb.w};
    #pragma unroll
    for (int h = 0; h < 8; h++){
      float v = pb[h];
      #pragma unroll
      for (int off = 32; off; off >>= 1) v += __shfl_xor(v, off, 64);
      if ((t & 63) == 0) redS[(t >> 6)*8 + h] = v;
    }
    __syncthreads();
    if (t < 8) basef[t] = redS[t] + redS[8+t] + redS[16+t] + redS[24+t] + bbS[t];
  }
  __syncthreads();
  // scores: wave cg handles channels [cg*64, cg*64+64), lanes = tokens
  const int s = t & 63, cg = t >> 6;
  const int gb = vt*HWK + sc*64;
  fcp fp = feats + ((size_t)vt*C_ + cg*64)*HWK + sc*64 + s;
  float acc[8] = {0,0,0,0,0,0,0,0};
  #pragma unroll 8
  for (int i = 0; i < 64; i++){
    const float fv = fp[(size_t)i*HWK];                 // coalesced over s
    const float4 wa = *(const float4*)&wf[(cg*64+i)*8]; // wave-uniform broadcast
    const float4 wb = *(const float4*)&wf[(cg*64+i)*8 + 4];
    acc[0] += fv*wa.x; acc[1] += fv*wa.y; acc[2] += fv*wa.z; acc[3] += fv*wa.w;
    acc[4] += fv*wb.x; acc[5] += fv*wb.y; acc[6] += fv*wb.z; acc[7] += fv*wb.w;
  }
  #pragma unroll
  for (int h = 0; h < 8; h++) pred[cg*512 + h*64 + s] = acc[h];
  __syncthreads();
  const int h1 = t >> 6;                // outputs o=t and o=t+256
  float s1 = pred[t]     + pred[512+t]     + pred[1024+t]     + pred[1536+t]     + basef[h1];
  float s2 = pred[256+t] + pred[512+256+t] + pred[1024+256+t] + pred[1536+256+t] + basef[h1+4];
  ws[SC_OFF + (size_t)h1*L_ + gb + s]     = s1;
  ws[SC_OFF + (size_t)(h1+4)*L_ + gb + s] = s2;
  float m1 = s1, m2 = s2;
  #pragma unroll
  for (int off = 32; off; off >>= 1){
    m1 = fmaxf(m1, __shfl_xor(m1, off, 64));
    m2 = fmaxf(m2, __shfl_xor(m2, off, 64));
  }
  if (s == 0){
    ws[PM_OFF + bid*8 + h1]     = m1;
    ws[PM_OFF + bid*8 + h1 + 4] = m2;
  }
}

// K3: global max per head (parallel scan), pex = exp(score-m), partial sums.
// 288 blocks = 18 vt x 16 s-chunks of 64; 256 threads (wave w owns heads 2w,2w+1).
__global__ void k_pexp(float* __restrict__ ws){
  __shared__ float pm2[256];
  __shared__ float mS[8];
  const int bid = blockIdx.x, vt = bid >> 4, sc = bid & 15, t = threadIdx.x;
  { // max over PM[288][8]: coalesced 9-round scan + LDS/shuffle tree
    float v = -1e30f;
    #pragma unroll
    for (int k = 0; k < 9; k++) v = fmaxf(v, ws[PM_OFF + t + 256*k]);
    pm2[t] = v;          // layout [p=t>>3][h=t&7]
    __syncthreads();
    if (t < 64){
      const int h2 = t & 7, q = t >> 3;
      float m = fmaxf(fmaxf(pm2[q*32 + h2], pm2[q*32 + 8 + h2]),
                      fmaxf(pm2[q*32 + 16 + h2], pm2[q*32 + 24 + h2]));
      m = fmaxf(m, __shfl_xor(m, 8, 64));
      m = fmaxf(m, __shfl_xor(m, 16, 64));
      m = fmaxf(m, __shfl_xor(m, 32, 64));
      if (t < 8) mS[t] = m;
    }
  }
  __syncthreads();
  const int s = t & 63, hh = t >> 6;     // wave hh -> heads 2hh, 2hh+1
  const int g = vt*HWK + sc*64 + s;
  const int h0 = hh*2;
  float e0 = __expf(ws[SC_OFF + (size_t)h0*L_ + g]     - mS[h0]);
  float e1 = __expf(ws[SC_OFF + (size_t)(h0+1)*L_ + g] - mS[h0+1]);
  *(float2*)(ws + PEX_OFF + (size_t)g*8 + h0) = make_float2(e0, e1);
  float v0 = e0, v1 = e1;
  #pragma unroll
  for (int off = 32; off; off >>= 1){
    v0 += __shfl_xor(v0, off, 64);
    v1 += __shfl_xor(v1, off, 64);
  }
  if (s == 0){
    ws[PS_OFF + bid*8 + h0]     = v0;
    ws[PS_OFF + bid*8 + h0 + 1] = v1;
  }
}

// K4: ctx[h][c] += sum_s pex[s][h]*feats[c][s].
// 1152 blocks = 18 vt x 16 c-chunks x 4 s-chunks; 256 threads = 4 waves x 4 channels.
__global__ void k_ctx(fcp feats, float* __restrict__ ws){
  const int bid = blockIdx.x;
  const int vt = bid / 64, r = bid - vt*64, cc = r & 15, ssi = r >> 4;
  const int t = threadIdx.x, wv = t >> 6, lane = t & 63;
  const int c0 = cc*16 + wv*4;
  fcp fb = feats + (size_t)vt*C_*HWK + ssi*256;
  const float* pexb = ws + PEX_OFF + ((size_t)vt*HWK + ssi*256)*8;
  float acc[4][8];
  #pragma unroll
  for (int j = 0; j < 4; j++)
    #pragma unroll
    for (int h = 0; h < 8; h++) acc[j][h] = 0.f;

  #pragma unroll
  for (int step = 0; step < 4; step++){
    const int s = step*64 + lane;
    const float4 pa = *(const float4*)(pexb + (size_t)s*8);
    const float4 pb = *(const float4*)(pexb + (size_t)s*8 + 4);
    #pragma unroll
    for (int j = 0; j < 4; j++){
      const float fv = fb[(size_t)(c0 + j)*HWK + s];      // coalesced
      acc[j][0] += fv*pa.x; acc[j][1] += fv*pa.y; acc[j][2] += fv*pa.z; acc[j][3] += fv*pa.w;
      acc[j][4] += fv*pb.x; acc[j][5] += fv*pb.y; acc[j][6] += fv*pb.z; acc[j][7] += fv*pb.w;
    }
  }
  #pragma unroll
  for (int j = 0; j < 4; j++)
    #pragma unroll
    for (int h = 0; h < 8; h++){
      float v = acc[j][h];
      #pragma unroll
      for (int off = 32; off; off >>= 1) v += __shfl_xor(v, off, 64);
      if (lane == j*8 + h) atomicAdd(ws + CTX_OFF + h*C_ + c0 + j, v);
    }
}

// K5: y[r] = v_w[r] . ctx_norm[head(r)] + v_b[r], embed/denominator correction.
__global__ void k_vproj(fcp vw, fcp vb, float* __restrict__ ws){
  __shared__ float psS[288*8];
  const int r = blockIdx.x, t = threadIdx.x, h = r >> 5;
  for (int i = t; i < 288*8; i += 256) psS[i] = ws[PS_OFF + i];
  __syncthreads();
  float denom = 0.f, embP = 0.f;
  for (int vt = 0; vt < VT_; vt++){
    float P = 0.f;
    #pragma unroll
    for (int sc2 = 0; sc2 < 16; sc2++) P += psS[(vt*16 + sc2)*8 + h];
    denom += P;
    embP  += ws[EMB_OFF + vt*C_ + t] * P;
  }
  const float ctxn = (ws[CTX_OFF + h*C_ + t] + embP) / denom;
  float v = vw[(size_t)r*C_ + t] * ctxn;
  v = blockReduceSum256(v);
  if (t == 0) ws[Y_OFF + r] = v + vb[r];
}

// K6: z = o_w @ y + o_b.
__global__ void k_oproj(fcp ow, fcp ob, float* __restrict__ ws){
  const int r = blockIdx.x, t = threadIdx.x;
  float v = ow[(size_t)r*C_ + t] * ws[Y_OFF + t];
  v = blockReduceSum256(v);
  if (t == 0) ws[Z_OFF + r] = v + ob[r];
}

// K7: LayerNorm over channels + broadcast store. 256 blocks (one channel) x 256.
__global__ void k_out(fcp lng, fcp lnb, const float* __restrict__ ws,
                      float* __restrict__ out, int hw){
  const int c = blockIdx.x, t = threadIdx.x;
  const float z = ws[Z_OFF + t];
  const float s  = blockReduceSum256(z);
  const float s2 = blockReduceSum256(z*z);
  const float mu = s * (1.f/C_);
  const float var = s2 * (1.f/C_) - mu*mu;
  const float rs = rsqrtf(var + 1e-5f);
  const float fin = (ws[Z_OFF + c] - mu) * rs * lng[c] + lnb[c];
  float4 pk = make_float4(fin, fin, fin, fin);
  ((float4*)(out + (size_t)c*hw))[t] = pk;   // 4 pixels per thread
}

extern "C" void kernel_launch(void* const* d_in, const int* in_sizes, int n_in,
                              void* d_out, int out_size, void* d_ws, size_t ws_size,
                              hipStream_t stream) {
  fcp feats = (fcp)d_in[0];
  fcp qe    = (fcp)d_in[1];
  fcp cam   = (fcp)d_in[2];
  fcp tpe   = (fcp)d_in[3];
  fcp spe   = (fcp)d_in[4];
  fcp qw    = (fcp)d_in[5];
  fcp qb    = (fcp)d_in[6];
  fcp kw    = (fcp)d_in[7];
  fcp kb    = (fcp)d_in[8];
  fcp vw    = (fcp)d_in[9];
  fcp vb    = (fcp)d_in[10];
  fcp ow    = (fcp)d_in[11];
  fcp ob    = (fcp)d_in[12];
  fcp lng   = (fcp)d_in[13];
  fcp lnb   = (fcp)d_in[14];
  const int* cidx = (const int*)d_in[15];
  float* ws = (float*)d_ws;
  float* out = (float*)d_out;
  const int hw = out_size / C_;   // 1024

  k_qp    <<<256,  256, 0, stream>>>(qe, cam, tpe, spe, cidx, qw, qb, ws);
  k_scores<<<288,  256, 0, stream>>>(feats, kw, kb, ws);
  k_pexp  <<<288,  256, 0, stream>>>(ws);
  k_ctx   <<<1152, 256, 0, stream>>>(feats, ws);
  k_vproj <<<256,  256, 0, stream>>>(vw, vb, ws);
  k_oproj <<<256,  256, 0, stream>>>(ow, ob, ws);
  k_out   <<<256,  256, 0, stream>>>(lng, lnb, ws, out, hw);
}